// Round 8
// baseline (147.142 us; speedup 1.0000x reference)
//
#include <hip/hip_runtime.h>
#include <math.h>
#include <stdint.h>

#define T_TOK 8192
#define NEXP  256
#define HD    7168
#define PLANE ((size_t)T_TOK * NEXP)
#define SCALE 4096.0f
#define INV_S2 (1.0f / 16777216.0f)   // 2^-24
#define BM 64
#define BK 32                          // fp32 K-columns per step
#define NSTEP_TOT (HD / BK)            // 224
#define IMG_STEP_H 16384               // halfs per K-step image (32 KB)

typedef _Float16 h8  __attribute__((ext_vector_type(8)));
typedef float f32x16 __attribute__((ext_vector_type(16)));

// ---- W -> f16 hi/lo image, [t][ks(2)][pl(2)][col(256)][kg(2)] in 8-half chunks ----
// chunk c within step: ks=c>>10, pl=(c>>9)&1, col=(c>>1)&255, kg=c&1.
// content: plane pl of W[col][t*32 + ks*16 + kg*8 .. +7] * SCALE.
__global__ __launch_bounds__(256) void wconv(const float* __restrict__ W,
                                             _Float16* __restrict__ img) {
  const int cc  = blockIdx.x * 256 + threadIdx.x;
  const int t   = cc >> 11;
  const int c   = cc & 2047;
  const int ks  = c >> 10;
  const int pl  = (c >> 9) & 1;
  const int col = (c >> 1) & 255;
  const int kg  = c & 1;
  const int k   = t * BK + ks * 16 + kg * 8;

  const float* src = W + (size_t)col * HD + k;
  const float4 v0 = *(const float4*)src;
  const float4 v1 = *(const float4*)(src + 4);
  const float xs[8] = {v0.x, v0.y, v0.z, v0.w, v1.x, v1.y, v1.z, v1.w};
  h8 out;
#pragma unroll
  for (int j = 0; j < 8; ++j) {
    const float v = xs[j] * SCALE;
    const _Float16 hh = (_Float16)v;
    out[j] = pl ? (_Float16)(v - (float)hh) : hh;
  }
  *(h8*)(img + (size_t)cc * 8) = out;
}

// ---- Router GEMM: 64x256 tile, 4 waves of 64x64; B direct from L2, A via small LDS ----
__global__ __launch_bounds__(256) void router_gemm(
    const float* __restrict__ X, const _Float16* __restrict__ img,
    float* __restrict__ partial, int S) {
  __shared__ _Float16 As[2][2][BM][BK];      // 16 KB total: [dbuf][pl][row][k]

  const int tid = threadIdx.x;
  const int id  = blockIdx.x;
  const int sb  = id % S;   // XCD = id%8 -> each XCD serves one sb -> 1.8 MB img slice L2-hot
  const int mb  = id / S;

  const int row0  = mb * BM;
  const int nstep = (HD / S) / BK;
  const int tbase = sb * nstep;

  const int lane = tid & 63, wv = tid >> 6;  // 4 waves: N-quarter each, wave tile 64(M)x64(N)
  const int r31 = lane & 31, kg = lane >> 5;

  const int sm = tid >> 2;                   // A staging row 0..63
  const int sk = tid & 3;                    // 8-float slot
  const int spA = sk ^ ((sm >> 1) & 3);      // XOR slot swizzle for conflict-lite A reads

  const float* Ap = X + (size_t)(row0 + sm) * HD + tbase * BK + sk * 8;

  // per-thread B half-offsets within a step image: [ks][pl][ni]
  // off = ((ks*2+pl)*256 + wv*64 + ni*32 + r31)*16 + kg*8
  const _Float16* imgBase = img + (size_t)tbase * IMG_STEP_H;
  const int colb = wv * 64 + r31;

  f32x16 acc[2][2];
#pragma unroll
  for (int i = 0; i < 2; ++i)
#pragma unroll
    for (int j = 0; j < 2; ++j) acc[i][j] = (f32x16)(0.f);

#define CVT_WRITE_A(b, va, vb)                                                 \
  {                                                                            \
    const float xs[8] = {va.x, va.y, va.z, va.w, vb.x, vb.y, vb.z, vb.w};      \
    h8 hv, lv_;                                                                \
    _Pragma("unroll")                                                          \
    for (int j = 0; j < 8; ++j) {                                              \
      const float v = xs[j] * SCALE;                                           \
      const _Float16 hh = (_Float16)v;                                         \
      hv[j] = hh; lv_[j] = (_Float16)(v - (float)hh);                          \
    }                                                                          \
    *(h8*)&As[b][0][sm][spA * 8] = hv;                                         \
    *(h8*)&As[b][1][sm][spA * 8] = lv_;                                        \
  }

  // prologue: stage A step 0
  {
    const float4 a0 = *(const float4*)(Ap);
    const float4 a1 = *(const float4*)(Ap + 4);
    CVT_WRITE_A(0, a0, a1);
  }

  for (int t = 0; t < nstep; ++t) {
    const int cur = t & 1;
    const bool more = (t + 1 < nstep);
    __syncthreads();                         // As[cur] visible to all waves

    // B loads for this step: 8 coalesced 16B reads/thread straight from L2
    const _Float16* bp = imgBase + (size_t)t * IMG_STEP_H;
    h8 b[2][2][2];                           // [ks][pl][ni]
#pragma unroll
    for (int ks = 0; ks < 2; ++ks)
#pragma unroll
      for (int pl = 0; pl < 2; ++pl)
#pragma unroll
        for (int ni = 0; ni < 2; ++ni)
          b[ks][pl][ni] = *(const h8*)(bp + ((size_t)((ks * 2 + pl) * 256 + colb + ni * 32) * 16) + kg * 8);

    // A prefetch for t+1 (global->regs; converted after MFMA)
    float4 a0, a1;
    if (more) {
      const float* ap = Ap + (size_t)(t + 1) * BK;
      a0 = *(const float4*)(ap);
      a1 = *(const float4*)(ap + 4);
    }

    // A fragments from LDS
    h8 aH[2][2], aL[2][2];                   // [ks][mi]
#pragma unroll
    for (int ks = 0; ks < 2; ++ks)
#pragma unroll
      for (int mi = 0; mi < 2; ++mi) {
        const int row = mi * 32 + r31;
        const int sp  = (ks * 2 + kg) ^ ((row >> 1) & 3);
        aH[ks][mi] = *(const h8*)&As[cur][0][row][sp * 8];
        aL[ks][mi] = *(const h8*)&As[cur][1][row][sp * 8];
      }

#pragma unroll
    for (int ks = 0; ks < 2; ++ks) {
#pragma unroll
      for (int mi = 0; mi < 2; ++mi)
#pragma unroll
        for (int ni = 0; ni < 2; ++ni)
          acc[mi][ni] = __builtin_amdgcn_mfma_f32_32x32x16_f16(aH[ks][mi], b[ks][0][ni], acc[mi][ni], 0, 0, 0);
#pragma unroll
      for (int mi = 0; mi < 2; ++mi)
#pragma unroll
        for (int ni = 0; ni < 2; ++ni)
          acc[mi][ni] = __builtin_amdgcn_mfma_f32_32x32x16_f16(aL[ks][mi], b[ks][0][ni], acc[mi][ni], 0, 0, 0);
#pragma unroll
      for (int mi = 0; mi < 2; ++mi)
#pragma unroll
        for (int ni = 0; ni < 2; ++ni)
          acc[mi][ni] = __builtin_amdgcn_mfma_f32_32x32x16_f16(aH[ks][mi], b[ks][1][ni], acc[mi][ni], 0, 0, 0);
    }

    if (more) {
      CVT_WRITE_A(cur ^ 1, a0, a1);          // write next buf; barrier at top of t+1 publishes
    }
  }

  // Epilogue. 32x32 C/D: col = lane&31, row = (reg&3) + 8*(reg>>2) + 4*(lane>>5)
  float* base = partial + (size_t)sb * PLANE;
#pragma unroll
  for (int mi = 0; mi < 2; ++mi)
#pragma unroll
    for (int ni = 0; ni < 2; ++ni) {
      const int col = wv * 64 + ni * 32 + r31;
#pragma unroll
      for (int reg = 0; reg < 16; ++reg) {
        const int rr  = (reg & 3) + 8 * (reg >> 2) + 4 * kg;
        const int row = row0 + mi * 32 + rr;
        base[(size_t)row * NEXP + col] = acc[mi][ni][reg];
      }
    }
}

// ---------------- Gating: one wave per token; sums S partial planes ----------------
__global__ __launch_bounds__(256) void gate_kernel(const float* __restrict__ logits,
                                                   const float* __restrict__ bias,
                                                   float* __restrict__ out_w,
                                                   float* __restrict__ out_e, int S) {
    const int wave = threadIdx.x >> 6;
    const int lane = threadIdx.x & 63;
    const int t = blockIdx.x * 4 + wave;
    if (t >= T_TOK) return;

    float l4[4] = {0.f, 0.f, 0.f, 0.f};
    for (int s = 0; s < S; ++s) {  // fixed order -> deterministic
        const float4 v = *(const float4*)(&logits[(size_t)s * PLANE + (size_t)t * NEXP + lane * 4]);
        l4[0] += v.x; l4[1] += v.y; l4[2] += v.z; l4[3] += v.w;
    }
    const float4 bv = *(const float4*)(&bias[lane * 4]);

    float s4[4], c[4];
#pragma unroll
    for (int j = 0; j < 4; ++j) s4[j] = 1.f / (1.f + expf(-l4[j] * INV_S2));
    c[0] = s4[0] + bv.x;
    c[1] = s4[1] + bv.y;
    c[2] = s4[2] + bv.z;
    c[3] = s4[3] + bv.w;

    float a = fmaxf(c[0], c[1]), b = fminf(c[0], c[1]);
    float d = fmaxf(c[2], c[3]), e = fminf(c[2], c[3]);
    float m1 = fmaxf(a, d);
    float m2 = fmaxf(fminf(a, d), fmaxf(b, e));
#pragma unroll
    for (int off = 1; off < 8; off <<= 1) {
        const float o1 = __shfl_xor(m1, off);
        const float o2 = __shfl_xor(m2, off);
        const float n1 = fmaxf(m1, o1);
        const float n2 = fmaxf(fminf(m1, o1), fmaxf(m2, o2));
        m1 = n1; m2 = n2;
    }
    const float gs = m1 + m2;
    const int   g  = lane >> 3;

    int rank = 0;
#pragma unroll
    for (int gg = 0; gg < 8; ++gg) {
        const float og = __shfl(gs, gg * 8);
        rank += (og > gs) || (og == gs && gg < g);
    }
    const bool gsel = rank < 4;

    float v[4];
#pragma unroll
    for (int j = 0; j < 4; ++j) v[j] = gsel ? c[j] : 0.0f;

    float selw = 0.f;
    int   seli = 0;
    float wsum = 0.f;

#pragma unroll
    for (int k = 0; k < 8; ++k) {
        float bvv = v[0]; int bi = lane * 4; float br = s4[0];
#pragma unroll
        for (int j = 1; j < 4; ++j) {
            if (v[j] > bvv) { bvv = v[j]; bi = lane * 4 + j; br = s4[j]; }
        }
#pragma unroll
        for (int off = 32; off > 0; off >>= 1) {
            const float ov = __shfl_xor(bvv, off);
            const int   oi = __shfl_xor(bi, off);
            const float orr = __shfl_xor(br, off);
            if (ov > bvv || (ov == bvv && oi < bi)) { bvv = ov; bi = oi; br = orr; }
        }
        if (lane == k) { selw = br; seli = bi; }
        wsum += br;
        const int rem = bi - lane * 4;
#pragma unroll
        for (int j = 0; j < 4; ++j)
            if (rem == j) v[j] = -INFINITY;
    }

    if (lane < 8) {
        const float w = selw / (wsum + 1e-20f) * 2.5f;
        out_w[(size_t)t * 8 + lane] = w;
        out_e[(size_t)t * 8 + lane] = (float)seli;
    }
}

extern "C" void kernel_launch(void* const* d_in, const int* in_sizes, int n_in,
                              void* d_out, int out_size, void* d_ws, size_t ws_size,
                              hipStream_t stream) {
    const float* X    = (const float*)d_in[0];
    const float* W    = (const float*)d_in[1];
    const float* bias = (const float*)d_in[2];
    float* out = (float*)d_out;

    _Float16* img = (_Float16*)d_ws;
    const size_t woff = (size_t)NSTEP_TOT * IMG_STEP_H * sizeof(_Float16);   // 7,340,032 B
    float* partial = (float*)((char*)d_ws + woff);

    int S = 1;
    if (ws_size >= woff + 4 * PLANE * sizeof(float)) S = 4;
    else if (ws_size >= woff + 2 * PLANE * sizeof(float)) S = 2;

    wconv<<<dim3(NSTEP_TOT * 2048 / 256), 256, 0, stream>>>(W, img);
    router_gemm<<<dim3((T_TOK / BM) * S), 256, 0, stream>>>(X, img, partial, S);
    gate_kernel<<<dim3(T_TOK / 4), 256, 0, stream>>>(partial, bias, out, out + (size_t)T_TOK * 8, S);
}

// Round 9
// 144.007 us; speedup vs baseline: 1.0218x; 1.0218x over previous
//
#include <hip/hip_runtime.h>
#include <math.h>
#include <stdint.h>

#define T_TOK 8192
#define NEXP  256
#define HD    7168
#define PLANE ((size_t)T_TOK * NEXP)
#define SCALE 4096.0f
#define INV_S2 (1.0f / 16777216.0f)   // 2^-24
#define BM 64
#define BK 32                          // fp32 K-columns per step
#define NSTEP_TOT (HD / BK)            // 224
#define IMG_STEP_H 16384               // halfs per K-step image (32 KB)

typedef _Float16 h8  __attribute__((ext_vector_type(8)));
typedef float f32x16 __attribute__((ext_vector_type(16)));

// ---- W -> f16 hi/lo image, [t][ks(2)][pl(2)][col(256)][kg(2)] in 8-half chunks ----
__global__ __launch_bounds__(256) void wconv(const float* __restrict__ W,
                                             _Float16* __restrict__ img) {
  const int cc  = blockIdx.x * 256 + threadIdx.x;
  const int t   = cc >> 11;
  const int c   = cc & 2047;
  const int ks  = c >> 10;
  const int pl  = (c >> 9) & 1;
  const int col = (c >> 1) & 255;
  const int kg  = c & 1;
  const int k   = t * BK + ks * 16 + kg * 8;

  const float* src = W + (size_t)col * HD + k;
  const float4 v0 = *(const float4*)src;
  const float4 v1 = *(const float4*)(src + 4);
  const float xs[8] = {v0.x, v0.y, v0.z, v0.w, v1.x, v1.y, v1.z, v1.w};
  h8 out;
#pragma unroll
  for (int j = 0; j < 8; ++j) {
    const float v = xs[j] * SCALE;
    const _Float16 hh = (_Float16)v;
    out[j] = pl ? (_Float16)(v - (float)hh) : hh;
  }
  *(h8*)(img + (size_t)cc * 8) = out;
}

// ---- Router GEMM: 64x256 tile, 4 waves of 64x64; B direct from L2, A via small LDS ----
__global__ __launch_bounds__(256) void router_gemm(
    const float* __restrict__ X, const _Float16* __restrict__ img,
    float* __restrict__ partial, int S) {
  __shared__ _Float16 As[2][2][BM][BK];      // 16 KB total: [dbuf][pl][row][k]

  const int tid = threadIdx.x;
  const int id  = blockIdx.x;
  const int sb  = id % S;   // S=8: XCD x serves only slice x -> 0.92 MB img slice L2-hot
  const int mb  = id / S;

  const int row0  = mb * BM;
  const int nstep = (HD / S) / BK;
  const int tbase = sb * nstep;

  const int lane = tid & 63, wv = tid >> 6;  // 4 waves: N-quarter each, wave tile 64(M)x64(N)
  const int r31 = lane & 31, kg = lane >> 5;

  const int sm = tid >> 2;                   // A staging row 0..63
  const int sk = tid & 3;                    // 8-float slot
  const int spA = sk ^ ((sm >> 1) & 3);      // XOR slot swizzle for conflict-lite A reads

  const float* Ap = X + (size_t)(row0 + sm) * HD + tbase * BK + sk * 8;

  const _Float16* imgBase = img + (size_t)tbase * IMG_STEP_H;
  const int colb = wv * 64 + r31;

  f32x16 acc[2][2];
#pragma unroll
  for (int i = 0; i < 2; ++i)
#pragma unroll
    for (int j = 0; j < 2; ++j) acc[i][j] = (f32x16)(0.f);

#define CVT_WRITE_A(b, va, vb)                                                 \
  {                                                                            \
    const float xs[8] = {va.x, va.y, va.z, va.w, vb.x, vb.y, vb.z, vb.w};      \
    h8 hv, lv_;                                                                \
    _Pragma("unroll")                                                          \
    for (int j = 0; j < 8; ++j) {                                              \
      const float v = xs[j] * SCALE;                                           \
      const _Float16 hh = (_Float16)v;                                         \
      hv[j] = hh; lv_[j] = (_Float16)(v - (float)hh);                          \
    }                                                                          \
    *(h8*)&As[b][0][sm][spA * 8] = hv;                                         \
    *(h8*)&As[b][1][sm][spA * 8] = lv_;                                        \
  }

  // prologue: stage A step 0
  {
    const float4 a0 = *(const float4*)(Ap);
    const float4 a1 = *(const float4*)(Ap + 4);
    CVT_WRITE_A(0, a0, a1);
  }

  for (int t = 0; t < nstep; ++t) {
    const int cur = t & 1;
    const bool more = (t + 1 < nstep);
    __syncthreads();                         // As[cur] visible to all waves

    // B loads for this step: 8 coalesced 16B reads/thread straight from L2
    const _Float16* bp = imgBase + (size_t)t * IMG_STEP_H;
    h8 b[2][2][2];                           // [ks][pl][ni]
#pragma unroll
    for (int ks = 0; ks < 2; ++ks)
#pragma unroll
      for (int pl = 0; pl < 2; ++pl)
#pragma unroll
        for (int ni = 0; ni < 2; ++ni)
          b[ks][pl][ni] = *(const h8*)(bp + ((size_t)((ks * 2 + pl) * 256 + colb + ni * 32) * 16) + kg * 8);

    // A prefetch for t+1 (global->regs; converted after MFMA)
    float4 a0, a1;
    if (more) {
      const float* ap = Ap + (size_t)(t + 1) * BK;
      a0 = *(const float4*)(ap);
      a1 = *(const float4*)(ap + 4);
    }

    // A fragments from LDS
    h8 aH[2][2], aL[2][2];                   // [ks][mi]
#pragma unroll
    for (int ks = 0; ks < 2; ++ks)
#pragma unroll
      for (int mi = 0; mi < 2; ++mi) {
        const int row = mi * 32 + r31;
        const int sp  = (ks * 2 + kg) ^ ((row >> 1) & 3);
        aH[ks][mi] = *(const h8*)&As[cur][0][row][sp * 8];
        aL[ks][mi] = *(const h8*)&As[cur][1][row][sp * 8];
      }

#pragma unroll
    for (int ks = 0; ks < 2; ++ks) {
#pragma unroll
      for (int mi = 0; mi < 2; ++mi)
#pragma unroll
        for (int ni = 0; ni < 2; ++ni)
          acc[mi][ni] = __builtin_amdgcn_mfma_f32_32x32x16_f16(aH[ks][mi], b[ks][0][ni], acc[mi][ni], 0, 0, 0);
#pragma unroll
      for (int mi = 0; mi < 2; ++mi)
#pragma unroll
        for (int ni = 0; ni < 2; ++ni)
          acc[mi][ni] = __builtin_amdgcn_mfma_f32_32x32x16_f16(aL[ks][mi], b[ks][0][ni], acc[mi][ni], 0, 0, 0);
#pragma unroll
      for (int mi = 0; mi < 2; ++mi)
#pragma unroll
        for (int ni = 0; ni < 2; ++ni)
          acc[mi][ni] = __builtin_amdgcn_mfma_f32_32x32x16_f16(aH[ks][mi], b[ks][1][ni], acc[mi][ni], 0, 0, 0);
    }

    if (more) {
      CVT_WRITE_A(cur ^ 1, a0, a1);          // write next buf; barrier at top of t+1 publishes
    }
  }

  // Epilogue. 32x32 C/D: col = lane&31, row = (reg&3) + 8*(reg>>2) + 4*(lane>>5)
  float* base = partial + (size_t)sb * PLANE;
#pragma unroll
  for (int mi = 0; mi < 2; ++mi)
#pragma unroll
    for (int ni = 0; ni < 2; ++ni) {
      const int col = wv * 64 + ni * 32 + r31;
#pragma unroll
      for (int reg = 0; reg < 16; ++reg) {
        const int rr  = (reg & 3) + 8 * (reg >> 2) + 4 * kg;
        const int row = row0 + mi * 32 + rr;
        base[(size_t)row * NEXP + col] = acc[mi][ni][reg];
      }
    }
}

// ---------------- Gating: one wave per token; sums S partial planes ----------------
__global__ __launch_bounds__(256) void gate_kernel(const float* __restrict__ logits,
                                                   const float* __restrict__ bias,
                                                   float* __restrict__ out_w,
                                                   float* __restrict__ out_e, int S) {
    const int wave = threadIdx.x >> 6;
    const int lane = threadIdx.x & 63;
    const int t = blockIdx.x * 4 + wave;
    if (t >= T_TOK) return;

    float l4[4] = {0.f, 0.f, 0.f, 0.f};
    for (int s = 0; s < S; ++s) {  // fixed order -> deterministic
        const float4 v = *(const float4*)(&logits[(size_t)s * PLANE + (size_t)t * NEXP + lane * 4]);
        l4[0] += v.x; l4[1] += v.y; l4[2] += v.z; l4[3] += v.w;
    }
    const float4 bv = *(const float4*)(&bias[lane * 4]);

    float s4[4], c[4];
#pragma unroll
    for (int j = 0; j < 4; ++j) s4[j] = 1.f / (1.f + expf(-l4[j] * INV_S2));
    c[0] = s4[0] + bv.x;
    c[1] = s4[1] + bv.y;
    c[2] = s4[2] + bv.z;
    c[3] = s4[3] + bv.w;

    float a = fmaxf(c[0], c[1]), b = fminf(c[0], c[1]);
    float d = fmaxf(c[2], c[3]), e = fminf(c[2], c[3]);
    float m1 = fmaxf(a, d);
    float m2 = fmaxf(fminf(a, d), fmaxf(b, e));
#pragma unroll
    for (int off = 1; off < 8; off <<= 1) {
        const float o1 = __shfl_xor(m1, off);
        const float o2 = __shfl_xor(m2, off);
        const float n1 = fmaxf(m1, o1);
        const float n2 = fmaxf(fminf(m1, o1), fmaxf(m2, o2));
        m1 = n1; m2 = n2;
    }
    const float gs = m1 + m2;
    const int   g  = lane >> 3;

    int rank = 0;
#pragma unroll
    for (int gg = 0; gg < 8; ++gg) {
        const float og = __shfl(gs, gg * 8);
        rank += (og > gs) || (og == gs && gg < g);
    }
    const bool gsel = rank < 4;

    float v[4];
#pragma unroll
    for (int j = 0; j < 4; ++j) v[j] = gsel ? c[j] : 0.0f;

    float selw = 0.f;
    int   seli = 0;
    float wsum = 0.f;

#pragma unroll
    for (int k = 0; k < 8; ++k) {
        float bvv = v[0]; int bi = lane * 4; float br = s4[0];
#pragma unroll
        for (int j = 1; j < 4; ++j) {
            if (v[j] > bvv) { bvv = v[j]; bi = lane * 4 + j; br = s4[j]; }
        }
#pragma unroll
        for (int off = 32; off > 0; off >>= 1) {
            const float ov = __shfl_xor(bvv, off);
            const int   oi = __shfl_xor(bi, off);
            const float orr = __shfl_xor(br, off);
            if (ov > bvv || (ov == bvv && oi < bi)) { bvv = ov; bi = oi; br = orr; }
        }
        if (lane == k) { selw = br; seli = bi; }
        wsum += br;
        const int rem = bi - lane * 4;
#pragma unroll
        for (int j = 0; j < 4; ++j)
            if (rem == j) v[j] = -INFINITY;
    }

    if (lane < 8) {
        const float w = selw / (wsum + 1e-20f) * 2.5f;
        out_w[(size_t)t * 8 + lane] = w;
        out_e[(size_t)t * 8 + lane] = (float)seli;
    }
}

extern "C" void kernel_launch(void* const* d_in, const int* in_sizes, int n_in,
                              void* d_out, int out_size, void* d_ws, size_t ws_size,
                              hipStream_t stream) {
    const float* X    = (const float*)d_in[0];
    const float* W    = (const float*)d_in[1];
    const float* bias = (const float*)d_in[2];
    float* out = (float*)d_out;

    _Float16* img = (_Float16*)d_ws;
    const size_t woff = (size_t)NSTEP_TOT * IMG_STEP_H * sizeof(_Float16);   // 7,340,032 B
    float* partial = (float*)((char*)d_ws + woff);

    // occupancy lever: S=8 -> 1024 blocks -> 4 blocks/CU (16 waves/CU)
    int S = 1;
    if (ws_size >= woff + 8 * PLANE * sizeof(float)) S = 8;
    else if (ws_size >= woff + 4 * PLANE * sizeof(float)) S = 4;
    else if (ws_size >= woff + 2 * PLANE * sizeof(float)) S = 2;

    wconv<<<dim3(NSTEP_TOT * 2048 / 256), 256, 0, stream>>>(W, img);
    router_gemm<<<dim3((T_TOK / BM) * S), 256, 0, stream>>>(X, img, partial, S);
    gate_kernel<<<dim3(T_TOK / 4), 256, 0, stream>>>(partial, bias, out, out + (size_t)T_TOK * 8, S);
}